// Round 11
// baseline (119.242 us; speedup 1.0000x reference)
//
#include <hip/hip_runtime.h>
#include <stdint.h>

// ---------------------------------------------------------------------------
// MoEBiEncoder: top-1 MoE (C=16 experts), per-row 768 -> relu(384) -> 768,
// gate-scale, l2norm, +residual, l2norm.  B=16384, D=768, H=384.
//
// v11: T3/T4 async-staging structure. B (and A) chunks staged into a 2-slot
//      LDS ring via global_load_lds; loads for step t+1 issued before
//      compute(t) and waited with per-wave vmcnt + raw s_barrier (no
//      __syncthreads drain in the K-loops). emb pre-converted to bf16 in
//      prep so A stages via gload_lds (gathered per-lane source, linear
//      LDS dest). M=32 tiles, 2-pass stage2, 78.2 KB LDS -> 2 blocks/CU.
// ---------------------------------------------------------------------------

#define B_ROWS 16384
#define C_EXP  16
#define D_DIM  768
#define H_DIM  384

typedef __bf16 bf16_t;
typedef __bf16 bf16x8 __attribute__((ext_vector_type(8)));
typedef float  f32x4  __attribute__((ext_vector_type(4)));

// ---- workspace layout (bytes) ----
static constexpr size_t WS_CNT  = 0;                       // 16 int
static constexpr size_t WS_CUR  = 64;                      // 16 int
static constexpr size_t WS_OFF  = 128;                     // 17 int
static constexpr size_t WS_TOFF = 256;                     // 17 int
static constexpr size_t WS_EXP  = 512;                     // B int
static constexpr size_t WS_GATE = WS_EXP  + (size_t)B_ROWS * 4;
static constexpr size_t WS_ROW  = WS_GATE + (size_t)B_ROWS * 4;
static constexpr size_t WS_W1   = WS_ROW  + (size_t)B_ROWS * 4;
static constexpr size_t W_BYTES = (size_t)C_EXP * D_DIM * H_DIM * 2;  // 9437184
static constexpr size_t WS_W4   = WS_W1 + W_BYTES;
static constexpr size_t WS_E16  = WS_W4 + W_BYTES;
static constexpr size_t E16_B   = (size_t)B_ROWS * D_DIM * 2;         // 25165824
static constexpr size_t WS_END  = WS_E16 + E16_B;          // ~43.4 MB

// Fragment-major weight layout (per expert, KF = K/32, NF = N/16):
//   frag(kf,nf) = 1024 contiguous bytes; lane l's 16B at l*16 hold
//   w[k0 + (l>>4)*8 + j][n0 + (l&15)], j=0..7.
// w1: KF=24, NF=24.  w4: KF=12, NF=48.
// -> one K-step's B-chunk (fixed kf, all nf) is CONTIGUOUS: 24 KB (w1),
//    and for w4 each 24-nf half is contiguous (2 N-passes).

__device__ __forceinline__ void lds_load16(const void* g, void* l) {
    auto gp = reinterpret_cast<const __attribute__((address_space(1))) uint32_t*>(
        reinterpret_cast<uintptr_t>(g));
    auto lp = reinterpret_cast<__attribute__((address_space(3))) uint32_t*>(
        reinterpret_cast<uintptr_t>(l));
    __builtin_amdgcn_global_load_lds(gp, lp, 16, 0, 0);
}

__device__ __forceinline__ f32x4 mfma16(bf16x8 a, bf16x8 b, f32x4 c) {
    return __builtin_amdgcn_mfma_f32_16x16x32_bf16(a, b, c, 0, 0, 0);
}

// ---------------------------------------------------------------------------
// Kernel 1 "prep": blocks 0..2303 convert weights; 2304..2335 gate;
// 2336..5407 convert emb fp32 -> bf16 (for gload_lds A staging).
// ---------------------------------------------------------------------------
__global__ __launch_bounds__(512) void prep(const float* __restrict__ w1,
                                            const float* __restrict__ w4,
                                            const float* __restrict__ logits,
                                            const float* __restrict__ emb,
                                            char* __restrict__ w1s,
                                            char* __restrict__ w4s,
                                            char* __restrict__ e16,
                                            int* __restrict__ expert,
                                            float* __restrict__ gatev,
                                            int* __restrict__ cnt) {
    __shared__ float tile[64 * 65];
    __shared__ int   hist[16];
    int bid = blockIdx.x;

    if (bid >= 2336) {
        // ---------------- emb fp32 -> bf16: 3072 blocks -------------------
        size_t idx = (size_t)(bid - 2336) * 4096 + threadIdx.x * 8;
        f32x4 f0 = *(const f32x4*)(emb + idx);
        f32x4 f1 = *(const f32x4*)(emb + idx + 4);
        bf16x8 p;
        p[0]=(bf16_t)f0[0]; p[1]=(bf16_t)f0[1]; p[2]=(bf16_t)f0[2]; p[3]=(bf16_t)f0[3];
        p[4]=(bf16_t)f1[0]; p[5]=(bf16_t)f1[1]; p[6]=(bf16_t)f1[2]; p[7]=(bf16_t)f1[3];
        *(bf16x8*)(e16 + idx * 2) = p;
        return;
    }
    if (bid >= 2304) {
        // ---------------- gate part: 32 blocks ----------------------------
        if (threadIdx.x < 16) hist[threadIdx.x] = 0;
        __syncthreads();
        int b = (bid - 2304) * 512 + threadIdx.x;   // 0..16383
        const f32x4* lp = (const f32x4*)(logits + (size_t)b * C_EXP);
        float l[16];
#pragma unroll
        for (int i = 0; i < 4; ++i) {
            f32x4 v = lp[i];
            l[i*4+0] = v[0]; l[i*4+1] = v[1]; l[i*4+2] = v[2]; l[i*4+3] = v[3];
        }
        float m = l[0]; int idx = 0;
#pragma unroll
        for (int j = 1; j < 16; ++j)
            if (l[j] > m) { m = l[j]; idx = j; }   // first-max == np.argmax
        float s = 0.f;
#pragma unroll
        for (int j = 0; j < 16; ++j) s += __expf((l[j] - m) * 0.1f);
        expert[b] = idx;
        gatev[b]  = 1.0f / s;
        atomicAdd(&hist[idx], 1);
        __syncthreads();
        if (threadIdx.x < 16) {
            int c = hist[threadIdx.x];
            if (c) atomicAdd(&cnt[threadIdx.x], c);
        }
        return;
    }

    // ---------------- weight convert: fp32 [K][N] -> bf16 fragment-major --
    bool is1 = bid < 1152;
    int lb = is1 ? bid : bid - 1152;
    int c = lb / 72, rem = lb % 72;
    int kc, nb, Nfull, KF, NF;
    const float* src;
    char* dstbase;
    if (is1) {
        kc = rem / 6;  nb = rem % 6;  Nfull = H_DIM; KF = 24; NF = 24;
        src     = w1 + (size_t)c * D_DIM * H_DIM;
        dstbase = w1s;
    } else {
        kc = rem / 12; nb = rem % 12; Nfull = D_DIM; KF = 12; NF = 48;
        src     = w4 + (size_t)c * H_DIM * D_DIM;
        dstbase = w4s;
    }
#pragma unroll
    for (int it = 0; it < 2; ++it) {
        int f  = threadIdx.x + it * 512;   // float4 id 0..1023
        int kr = f >> 4, nq = f & 15;
        f32x4 v = *(const f32x4*)(src + (size_t)(kc * 64 + kr) * Nfull + nb * 64 + nq * 4);
        tile[kr * 65 + nq * 4 + 0] = v[0];
        tile[kr * 65 + nq * 4 + 1] = v[1];
        tile[kr * 65 + nq * 4 + 2] = v[2];
        tile[kr * 65 + nq * 4 + 3] = v[3];
    }
    __syncthreads();
    {
        int frag = threadIdx.x >> 6, lane = threadIdx.x & 63;
        int kfl  = frag >> 2, nfl = frag & 3;
        int col  = lane & 15, kq = lane >> 4;
        bf16x8 p;
#pragma unroll
        for (int j = 0; j < 8; ++j)
            p[j] = (bf16_t)tile[(kfl * 32 + kq * 8 + j) * 65 + nfl * 16 + col];
        int kf = kc * 2 + kfl, nf = nb * 4 + nfl;
        size_t off = (((size_t)c * KF + kf) * NF + nf) * 1024 + lane * 16;
        *(bf16x8*)(dstbase + off) = p;
    }
}

// ---------------------------------------------------------------------------
// Kernel 2: tiny serial scan (16 experts), 32-row tiles.
// ---------------------------------------------------------------------------
__global__ void scank(const int* __restrict__ cnt, int* __restrict__ offs,
                      int* __restrict__ toff) {
    if (threadIdx.x == 0 && blockIdx.x == 0) {
        int o = 0, to = 0;
        for (int e = 0; e < C_EXP; ++e) {
            offs[e] = o; toff[e] = to;
            o  += cnt[e];
            to += (cnt[e] + 31) >> 5;
        }
        offs[C_EXP] = o; toff[C_EXP] = to;
    }
}

// ---------------------------------------------------------------------------
// Kernel 3: bucket rows by expert (hierarchical: LDS rank + 16 atomics/blk).
// ---------------------------------------------------------------------------
__global__ __launch_bounds__(512) void scatk(const int* __restrict__ expert,
                                             const int* __restrict__ offs,
                                             int* __restrict__ cursor,
                                             int* __restrict__ rowlist) {
    __shared__ int lcur[16], lbase[16];
    int b = blockIdx.x * 512 + threadIdx.x;
    if (threadIdx.x < 16) lcur[threadIdx.x] = 0;
    __syncthreads();
    int e = expert[b];
    int p = atomicAdd(&lcur[e], 1);
    __syncthreads();
    if (threadIdx.x < 16) {
        int c = lcur[threadIdx.x];
        lbase[threadIdx.x] = c ? atomicAdd(&cursor[threadIdx.x], c) : 0;
    }
    __syncthreads();
    rowlist[offs[e] + lbase[e] + p] = b;
}

// ---------------------------------------------------------------------------
// Kernel 4: grouped GEMM + fused epilogue, async-staged (T3/T4).
// One block = 32 rows, 512 threads = 8 waves, pure N-split.
// LDS (80128 B):
//   ring 2 x 26624 @0      stage1 entry: A 2 KB (frag rgp 0,1) + B 24 KB
//                          stage2 entry: B 24 KB (one N-half)
//   h    24576     @53248  [12 kf][2 rgp] x 1 KB fragment-major
//   ssb1 @77824  ssb2 @78848  ridx @79872  gate @80000
// K-loop: STAGE(t+1) issued before compute(t); own-wave vmcnt(0) + raw
// s_barrier per step (loads fly during a full compute step ~>= latency).
// ---------------------------------------------------------------------------
#define RSTRIDE 26624
#define HOFF    53248
#define SMEM_BYTES 80128

__global__ __launch_bounds__(512, 4) void moe_main(
    const float* __restrict__ emb, const char* __restrict__ emb16,
    const float* __restrict__ gatev,
    const int* __restrict__ rowlist, const int* __restrict__ cnt,
    const int* __restrict__ offs, const int* __restrict__ toff,
    const char* __restrict__ w1s, const char* __restrict__ w4s,
    const float* __restrict__ b1, const float* __restrict__ b4,
    float* __restrict__ out) {
    extern __shared__ char smem[];

    // XCD-aware bijective swizzle: grid 528 = 8 * 66
    int bid = blockIdx.x;
    int t0  = (bid & 7) * 66 + (bid >> 3);

    int total = toff[C_EXP];
    if (t0 >= total) return;
    int e = 0;
#pragma unroll
    for (int i = 1; i < C_EXP; ++i) e = (t0 >= toff[i]) ? i : e;
    int tin  = t0 - toff[e];
    int Meff = cnt[e] - tin * 32; if (Meff > 32) Meff = 32;
    int base = offs[e] + tin * 32;

    float* ssb1  = (float*)(smem + 77824);   // [32][8]
    float* ssb2  = (float*)(smem + 78848);   // [32][8]
    int*   ridxL = (int*)(smem + 79872);
    float* gateL = (float*)(smem + 80000);
    if (threadIdx.x < 32) {
        int rr = threadIdx.x;
        int p  = base + (rr < Meff ? rr : 0);
        int ri = rowlist[p];
        ridxL[rr] = ri;
        gateL[rr] = gatev[ri];
    }
    __syncthreads();   // ridxL visible (full drain, once)

    const int wid  = threadIdx.x >> 6;
    const int lane = threadIdx.x & 63;
    const int l15  = lane & 15, l4 = lane >> 4;

    const char* w1e = w1s + (size_t)e * 589824;
    const char* w4e = w4s + (size_t)e * 589824;

    // per-lane gathered A source (waves 0,1 stage A-frag rgp = wid)
    const char* a_src = emb16;   // dummy init
    if (wid < 2)
        a_src = emb16 + (size_t)ridxL[wid * 16 + l15] * (D_DIM * 2) + l4 * 16;

    auto STAGE1 = [&](int kf, int slot) {
        char* eb = smem + slot * RSTRIDE;
#pragma unroll
        for (int i = 0; i < 3; ++i)
            lds_load16(w1e + ((size_t)(kf * 24 + wid * 3 + i) << 10) + lane * 16,
                       eb + 2048 + (wid * 3 + i) * 1024 + lane * 16);
        if (wid < 2)
            lds_load16(a_src + kf * 64, eb + wid * 1024 + lane * 16);
    };
    auto STAGE2 = [&](int s, int slot) {
        int p = s / 12, kf = s % 12;
        char* eb = smem + slot * RSTRIDE;
#pragma unroll
        for (int i = 0; i < 3; ++i)
            lds_load16(w4e + ((size_t)(kf * 48 + p * 24 + wid * 3 + i) << 10) + lane * 16,
                       eb + (wid * 3 + i) * 1024 + lane * 16);
    };

    // ---------------- stage 1: h = relu(emb @ w1 + b1)  [32x384] ----------
    f32x4 acc1[2][3];
#pragma unroll
    for (int rg = 0; rg < 2; ++rg)
#pragma unroll
        for (int j = 0; j < 3; ++j) acc1[rg][j] = f32x4{0.f, 0.f, 0.f, 0.f};

    STAGE1(0, 0);
#pragma unroll
    for (int t = 0; t < 24; ++t) {
        asm volatile("s_waitcnt vmcnt(0)" ::: "memory");   // own staged loads landed
        __builtin_amdgcn_s_barrier();                      // everyone's landed
        __builtin_amdgcn_sched_barrier(0);
        if (t + 1 < 24) STAGE1(t + 1, (t + 1) & 1);        // async next chunk
        __builtin_amdgcn_sched_barrier(0);                 // keep issue above MFMAs
        const char* eb = smem + (t & 1) * RSTRIDE;
        bf16x8 a0 = *(const bf16x8*)(eb + lane * 16);
        bf16x8 a1 = *(const bf16x8*)(eb + 1024 + lane * 16);
        bf16x8 b0 = *(const bf16x8*)(eb + 2048 + (wid * 3 + 0) * 1024 + lane * 16);
        bf16x8 bv1 = *(const bf16x8*)(eb + 2048 + (wid * 3 + 1) * 1024 + lane * 16);
        bf16x8 bv2 = *(const bf16x8*)(eb + 2048 + (wid * 3 + 2) * 1024 + lane * 16);
        acc1[0][0] = mfma16(a0, b0,  acc1[0][0]);
        acc1[1][0] = mfma16(a1, b0,  acc1[1][0]);
        acc1[0][1] = mfma16(a0, bv1, acc1[0][1]);
        acc1[1][1] = mfma16(a1, bv1, acc1[1][1]);
        acc1[0][2] = mfma16(a0, bv2, acc1[0][2]);
        acc1[1][2] = mfma16(a1, bv2, acc1[1][2]);
    }

    // h = relu(acc1 + b1) -> fragment-major [12 kf][2 rgp] @ HOFF
#pragma unroll
    for (int jn = 0; jn < 3; ++jn) {
        int hcol = wid * 48 + jn * 16 + l15;
        float bb = b1[e * H_DIM + hcol];
        int fb = ((hcol >> 5) * 2) * 1024 + (((hcol >> 3) & 3) * 16) * 16 + (hcol & 7) * 2;
#pragma unroll
        for (int rg = 0; rg < 2; ++rg)
#pragma unroll
            for (int v = 0; v < 4; ++v) {
                int rl = l4 * 4 + v;   // row & 15
                float hv = fmaxf(acc1[rg][jn][v] + bb, 0.f);
                *(bf16_t*)(smem + HOFF + fb + rg * 1024 + rl * 16) = (bf16_t)hv;
            }
    }
    asm volatile("s_waitcnt lgkmcnt(0)" ::: "memory");
    __builtin_amdgcn_s_barrier();                          // h visible
    __builtin_amdgcn_sched_barrier(0);

    // ---------------- stage 2: eo = h @ w4  [32x768], 2 N-passes ----------
    f32x4 acc2[2][2][3];   // [pass][rg][jn]
#pragma unroll
    for (int p = 0; p < 2; ++p)
#pragma unroll
        for (int rg = 0; rg < 2; ++rg)
#pragma unroll
            for (int j = 0; j < 3; ++j) acc2[p][rg][j] = f32x4{0.f, 0.f, 0.f, 0.f};

    STAGE2(0, 0);
#pragma unroll
    for (int s = 0; s < 24; ++s) {
        asm volatile("s_waitcnt vmcnt(0)" ::: "memory");
        __builtin_amdgcn_s_barrier();
        __builtin_amdgcn_sched_barrier(0);
        if (s + 1 < 24) STAGE2(s + 1, (s + 1) & 1);
        __builtin_amdgcn_sched_barrier(0);
        const int p = s / 12, kf = s % 12;
        const char* eb = smem + (s & 1) * RSTRIDE;
        bf16x8 a0 = *(const bf16x8*)(smem + HOFF + (kf * 2 + 0) * 1024 + lane * 16);
        bf16x8 a1 = *(const bf16x8*)(smem + HOFF + (kf * 2 + 1) * 1024 + lane * 16);
        bf16x8 b0 = *(const bf16x8*)(eb + (wid * 3 + 0) * 1024 + lane * 16);
        bf16x8 bv1 = *(const bf16x8*)(eb + (wid * 3 + 1) * 1024 + lane * 16);
        bf16x8 bv2 = *(const bf16x8*)(eb + (wid * 3 + 2) * 1024 + lane * 16);
        acc2[p][0][0] = mfma16(a0, b0,  acc2[p][0][0]);
        acc2[p][1][0] = mfma16(a1, b0,  acc2[p][1][0]);
        acc2[p][0][1] = mfma16(a0, bv1, acc2[p][0][1]);
        acc2[p][1][1] = mfma16(a1, bv1, acc2[p][1][1]);
        acc2[p][0][2] = mfma16(a0, bv2, acc2[p][0][2]);
        acc2[p][1][2] = mfma16(a1, bv2, acc2[p][1][2]);
    }

    // ---------------- epilogue: gate, l2norm, +emb, l2norm, scatter -------
    // wave's cols: p*384 + wid*48 + jn*16 + l15  (p 0..1, jn 0..2)
    float part[2][4];
#pragma unroll
    for (int rg = 0; rg < 2; ++rg)
#pragma unroll
        for (int v = 0; v < 4; ++v) part[rg][v] = 0.f;

#pragma unroll
    for (int p = 0; p < 2; ++p)
#pragma unroll
        for (int jn = 0; jn < 3; ++jn) {
            float bb = b4[e * D_DIM + p * 384 + wid * 48 + jn * 16 + l15];
#pragma unroll
            for (int rg = 0; rg < 2; ++rg)
#pragma unroll
                for (int v = 0; v < 4; ++v) {
                    float cv = (acc2[p][rg][jn][v] + bb) * gateL[rg * 16 + l4 * 4 + v];
                    acc2[p][rg][jn][v] = cv;
                    part[rg][v] += cv * cv;
                }
        }
#pragma unroll
    for (int o = 1; o < 16; o <<= 1)
#pragma unroll
        for (int rg = 0; rg < 2; ++rg)
#pragma unroll
            for (int v = 0; v < 4; ++v) part[rg][v] += __shfl_xor(part[rg][v], o, 64);
    if (l15 == 0)
#pragma unroll
        for (int rg = 0; rg < 2; ++rg)
#pragma unroll
            for (int v = 0; v < 4; ++v) ssb1[(rg * 16 + l4 * 4 + v) * 8 + wid] = part[rg][v];
    __syncthreads();

    int   rofs[2][4];
    float inv1[2][4];
#pragma unroll
    for (int rg = 0; rg < 2; ++rg)
#pragma unroll
        for (int v = 0; v < 4; ++v) {
            int row = rg * 16 + l4 * 4 + v;
            rofs[rg][v] = ridxL[row] * D_DIM;
            float s = 0.f;
#pragma unroll
            for (int w = 0; w < 8; ++w) s += ssb1[row * 8 + w];
            inv1[rg][v] = 1.0f / fmaxf(sqrtf(s), 1e-6f);
        }

    float part2[2][4];
#pragma unroll
    for (int rg = 0; rg < 2; ++rg)
#pragma unroll
        for (int v = 0; v < 4; ++v) part2[rg][v] = 0.f;

#pragma unroll
    for (int p = 0; p < 2; ++p)
#pragma unroll
        for (int jn = 0; jn < 3; ++jn) {
            int col = p * 384 + wid * 48 + jn * 16 + l15;
#pragma unroll
            for (int rg = 0; rg < 2; ++rg)
#pragma unroll
                for (int v = 0; v < 4; ++v) {
                    float em = emb[rofs[rg][v] + col];
                    float o2 = acc2[p][rg][jn][v] * inv1[rg][v] + em;
                    acc2[p][rg][jn][v] = o2;
                    part2[rg][v] += o2 * o2;
                }
        }
#pragma unroll
    for (int o = 1; o < 16; o <<= 1)
#pragma unroll
        for (int rg = 0; rg < 2; ++rg)
#pragma unroll
            for (int v = 0; v < 4; ++v) part2[rg][v] += __shfl_xor(part2[rg][v], o, 64);
    if (l15 == 0)
#pragma unroll
        for (int rg = 0; rg < 2; ++rg)
#pragma unroll
            for (int v = 0; v < 4; ++v) ssb2[(rg * 16 + l4 * 4 + v) * 8 + wid] = part2[rg][v];
    __syncthreads();

#pragma unroll
    for (int rg = 0; rg < 2; ++rg)
#pragma unroll
        for (int v = 0; v < 4; ++v) {
            int row = rg * 16 + l4 * 4 + v;
            float s = 0.f;
#pragma unroll
            for (int w = 0; w < 8; ++w) s += ssb2[row * 8 + w];
            float inv2 = 1.0f / fmaxf(sqrtf(s), 1e-12f);
            if (row < Meff) {
#pragma unroll
                for (int p = 0; p < 2; ++p)
#pragma unroll
                    for (int jn = 0; jn < 3; ++jn)
                        out[rofs[rg][v] + p * 384 + wid * 48 + jn * 16 + l15] =
                            acc2[p][rg][jn][v] * inv2;
            }
        }
}

// ---------------------------------------------------------------------------
extern "C" void kernel_launch(void* const* d_in, const int* in_sizes, int n_in,
                              void* d_out, int out_size, void* d_ws, size_t ws_size,
                              hipStream_t stream) {
    const float* emb    = (const float*)d_in[0];
    const float* logits = (const float*)d_in[1];
    const float* w1     = (const float*)d_in[2];
    const float* b1     = (const float*)d_in[3];
    const float* w4     = (const float*)d_in[4];
    const float* b4     = (const float*)d_in[5];
    float* out = (float*)d_out;
    char*  ws  = (char*)d_ws;
    if (ws_size < WS_END) return;  // workspace too small -> fail loudly

    int*   cnt     = (int*)(ws + WS_CNT);
    int*   cur     = (int*)(ws + WS_CUR);
    int*   offs    = (int*)(ws + WS_OFF);
    int*   toff    = (int*)(ws + WS_TOFF);
    int*   expert  = (int*)(ws + WS_EXP);
    float* gatev   = (float*)(ws + WS_GATE);
    int*   rowlist = (int*)(ws + WS_ROW);
    char*  w1s     = ws + WS_W1;
    char*  w4s     = ws + WS_W4;
    char*  e16     = ws + WS_E16;

    hipMemsetAsync(ws, 0, 512, stream);
    // weights (2304) + gate (32) + emb->bf16 (3072) in one dispatch
    prep<<<dim3(5408), dim3(512), 0, stream>>>(w1, w4, logits, emb,
                                               w1s, w4s, e16,
                                               expert, gatev, cnt);
    scank<<<dim3(1), dim3(64), 0, stream>>>(cnt, offs, toff);
    scatk<<<dim3(32), dim3(512), 0, stream>>>(expert, offs, cur, rowlist);

    (void)hipFuncSetAttribute((const void*)moe_main,
                              hipFuncAttributeMaxDynamicSharedMemorySize, SMEM_BYTES);
    // max tiles = sum_e ceil(cnt_e/32) <= 527; grid 528 = 8*66 (swizzle)
    moe_main<<<dim3(528), dim3(512), SMEM_BYTES, stream>>>(
        emb, e16, gatev, rowlist, cnt, offs, toff, w1s, w4s, b1, b4, out);
}

// Round 12
// 91.785 us; speedup vs baseline: 1.2991x; 1.2991x over previous
//
#include <hip/hip_runtime.h>
#include <stdint.h>

// ---------------------------------------------------------------------------
// MoEBiEncoder: top-1 MoE (C=16 experts), per-row 768 -> relu(384) -> 768,
// gate-scale, l2norm, +residual, l2norm.  B=16384, D=768, H=384.
//
// v12: consolidation to best-known (R5 shape, plain loops) +
//      - scank dispatch removed (scatk/moe_main derive prefix sums locally)
//      - s_setprio(1) around MFMA clusters (T5; resident blocks are at
//        different phases here, matching the case where setprio helps)
//      - e16/NT/prefetch experiments all reverted (measured <= neutral)
// ---------------------------------------------------------------------------

#define B_ROWS 16384
#define C_EXP  16
#define D_DIM  768
#define H_DIM  384

typedef __bf16 bf16_t;
typedef __bf16 bf16x8 __attribute__((ext_vector_type(8)));
typedef float  f32x4  __attribute__((ext_vector_type(4)));

// ---- workspace layout (bytes) ----
static constexpr size_t WS_CNT  = 0;                       // 16 int
static constexpr size_t WS_CUR  = 64;                      // 16 int
static constexpr size_t WS_EXP  = 512;                     // B int
static constexpr size_t WS_GATE = WS_EXP  + (size_t)B_ROWS * 4;
static constexpr size_t WS_ROW  = WS_GATE + (size_t)B_ROWS * 4;
static constexpr size_t WS_W1   = WS_ROW  + (size_t)B_ROWS * 4;
static constexpr size_t W_BYTES = (size_t)C_EXP * D_DIM * H_DIM * 2;  // 9437184
static constexpr size_t WS_W4   = WS_W1 + W_BYTES;
static constexpr size_t WS_END  = WS_W4 + W_BYTES;         // ~18.2 MB

// Fragment-major weight layout (per expert, KF = K/32, NF = N/16):
//   frag(kf,nf) = 1024 contiguous bytes; lane l's 16B at l*16 hold
//   w[k0 + (l>>4)*8 + j][n0 + (l&15)], j=0..7.
// w1: KF=24, NF=24.  w4: KF=12, NF=48.

__device__ __forceinline__ f32x4 mfma16(bf16x8 a, bf16x8 b, f32x4 c) {
    return __builtin_amdgcn_mfma_f32_16x16x32_bf16(a, b, c, 0, 0, 0);
}

// ---------------------------------------------------------------------------
// Kernel 1 "prep": blocks 0..2303 convert weights; blocks 2304..2335 do the
// gate (softmax/argmax) + per-expert counts via LDS histogram.
// ---------------------------------------------------------------------------
__global__ __launch_bounds__(512) void prep(const float* __restrict__ w1,
                                            const float* __restrict__ w4,
                                            const float* __restrict__ logits,
                                            char* __restrict__ w1s,
                                            char* __restrict__ w4s,
                                            int* __restrict__ expert,
                                            float* __restrict__ gatev,
                                            int* __restrict__ cnt) {
    __shared__ float tile[64 * 65];
    __shared__ int   hist[16];
    int bid = blockIdx.x;

    if (bid >= 2304) {
        // ---------------- gate part: 32 blocks x 512 threads --------------
        if (threadIdx.x < 16) hist[threadIdx.x] = 0;
        __syncthreads();
        int b = (bid - 2304) * 512 + threadIdx.x;   // 0..16383
        const f32x4* lp = (const f32x4*)(logits + (size_t)b * C_EXP);
        float l[16];
#pragma unroll
        for (int i = 0; i < 4; ++i) {
            f32x4 v = lp[i];
            l[i*4+0] = v[0]; l[i*4+1] = v[1]; l[i*4+2] = v[2]; l[i*4+3] = v[3];
        }
        float m = l[0]; int idx = 0;
#pragma unroll
        for (int j = 1; j < 16; ++j)
            if (l[j] > m) { m = l[j]; idx = j; }   // first-max == np.argmax
        float s = 0.f;
#pragma unroll
        for (int j = 0; j < 16; ++j) s += __expf((l[j] - m) * 0.1f);
        expert[b] = idx;
        gatev[b]  = 1.0f / s;          // softmax value at the argmax
        atomicAdd(&hist[idx], 1);      // LDS atomic (fast)
        __syncthreads();
        if (threadIdx.x < 16) {
            int c = hist[threadIdx.x];
            if (c) atomicAdd(&cnt[threadIdx.x], c);   // <=16 global atomics/blk
        }
        return;
    }

    // ---------------- weight convert: fp32 [K][N] -> bf16 fragment-major --
    bool is1 = bid < 1152;
    int lb = is1 ? bid : bid - 1152;
    int c = lb / 72, rem = lb % 72;
    int kc, nb, Nfull, KF, NF;
    const float* src;
    char* dstbase;
    if (is1) {
        kc = rem / 6;  nb = rem % 6;  Nfull = H_DIM; KF = 24; NF = 24;
        src     = w1 + (size_t)c * D_DIM * H_DIM;
        dstbase = w1s;
    } else {
        kc = rem / 12; nb = rem % 12; Nfull = D_DIM; KF = 12; NF = 48;
        src     = w4 + (size_t)c * H_DIM * D_DIM;
        dstbase = w4s;
    }
    // read 64(k) x 64(n) fp32 tile, coalesced along n
#pragma unroll
    for (int it = 0; it < 2; ++it) {
        int f  = threadIdx.x + it * 512;   // float4 id 0..1023
        int kr = f >> 4, nq = f & 15;
        f32x4 v = *(const f32x4*)(src + (size_t)(kc * 64 + kr) * Nfull + nb * 64 + nq * 4);
        tile[kr * 65 + nq * 4 + 0] = v[0];
        tile[kr * 65 + nq * 4 + 1] = v[1];
        tile[kr * 65 + nq * 4 + 2] = v[2];
        tile[kr * 65 + nq * 4 + 3] = v[3];
    }
    __syncthreads();
    // write 8 fragments (one per 64-thread group), 16B/lane coalesced
    {
        int frag = threadIdx.x >> 6, lane = threadIdx.x & 63;
        int kfl  = frag >> 2, nfl = frag & 3;
        int col  = lane & 15, kq = lane >> 4;
        bf16x8 p;
#pragma unroll
        for (int j = 0; j < 8; ++j)
            p[j] = (bf16_t)tile[(kfl * 32 + kq * 8 + j) * 65 + nfl * 16 + col];
        int kf = kc * 2 + kfl, nf = nb * 4 + nfl;
        size_t off = (((size_t)c * KF + kf) * NF + nf) * 1024 + lane * 16;
        *(bf16x8*)(dstbase + off) = p;
    }
}

// ---------------------------------------------------------------------------
// Kernel 2: bucket rows by expert. offs derived in-block from cnt (prefix of
// 16 values) -> no separate scan dispatch. Hierarchical cursor atomics.
// ---------------------------------------------------------------------------
__global__ __launch_bounds__(512) void scatk(const int* __restrict__ expert,
                                             const int* __restrict__ cnt,
                                             int* __restrict__ cursor,
                                             int* __restrict__ rowlist) {
    __shared__ int lcnt[16], lcur[16], lbase[16];
    int b = blockIdx.x * 512 + threadIdx.x;   // grid 32 -> 0..16383
    if (threadIdx.x < 16) {
        lcnt[threadIdx.x] = cnt[threadIdx.x];
        lcur[threadIdx.x] = 0;
    }
    __syncthreads();
    int e = expert[b];
    int off = 0;
#pragma unroll
    for (int i = 0; i < 16; ++i) off += (i < e) ? lcnt[i] : 0;
    int p = atomicAdd(&lcur[e], 1);           // LDS atomic
    __syncthreads();
    if (threadIdx.x < 16) {
        int c = lcur[threadIdx.x];
        lbase[threadIdx.x] = c ? atomicAdd(&cursor[threadIdx.x], c) : 0;
    }
    __syncthreads();
    rowlist[off + lbase[e] + p] = b;
}

// ---------------------------------------------------------------------------
// Kernel 3: grouped GEMM + fused epilogue (R5 structure, consolidated).
// One block = 32 rows of one expert, 512 threads = 8 waves (N-split).
// LDS (51456 B):
//   [0, 49152)  embA [32][768] bf16 swz (stage 1)
//   [0, 24576)  h    [32][384] bf16 swz (stage 2; aliases dead embA)
//   ssb1 @49152 (1 KB); ssb2 @50176 (1 KB); ridx @51200; gate @51328.
// Tile->expert mapping derived in-block from cnt[16] (scalar prefix).
// s_setprio(1) around MFMA clusters (T5).
// ---------------------------------------------------------------------------
#define SMEM_BYTES 51456

__global__ __launch_bounds__(512, 4) void moe_main(
    const float* __restrict__ emb, const float* __restrict__ gatev,
    const int* __restrict__ rowlist, const int* __restrict__ cnt,
    const char* __restrict__ w1s, const char* __restrict__ w4s,
    const float* __restrict__ b1, const float* __restrict__ b4,
    float* __restrict__ out) {
    extern __shared__ char smem[];

    // XCD-aware bijective swizzle: grid 528 = 8 * 66
    int bid = blockIdx.x;
    int t   = (bid & 7) * 66 + (bid >> 3);

    // derive (e, tin, base, Meff) from cnt[16] with a scalar prefix scan
    int e = -1, tin = 0, base = 0, cnte = 0;
    {
        int to = 0, o = 0;
#pragma unroll
        for (int i = 0; i < 16; ++i) {
            int ci = cnt[i];
            int tc = (ci + 31) >> 5;
            if (e < 0 && t >= to && t < to + tc) {
                e = i; tin = t - to; base = o + (t - to) * 32; cnte = ci;
            }
            to += tc; o += ci;
        }
    }
    if (e < 0) return;   // beyond total tiles
    int Meff = cnte - tin * 32; if (Meff > 32) Meff = 32;

    float* ssb1  = (float*)(smem + 49152);   // [32][8]
    float* ssb2  = (float*)(smem + 50176);   // [32][8]
    int*   ridxL = (int*)(smem + 51200);
    float* gateL = (float*)(smem + 51328);
    if (threadIdx.x < 32) {
        int rr = threadIdx.x;
        int p  = base + (rr < Meff ? rr : 0);   // clamp pad rows
        int ri = rowlist[p];
        ridxL[rr] = ri;
        gateL[rr] = gatev[ri];
    }
    __syncthreads();   // (1) ridxL visible

    const int wid  = threadIdx.x >> 6;
    const int lane = threadIdx.x & 63;
    const int l15  = lane & 15, l4 = lane >> 4;

    const char* w1e = w1s + (size_t)e * 589824;
    const char* w4e = w4s + (size_t)e * 589824;

    // ---- stage embA: fp32 -> bf16, swizzled [32][768] --------------------
#pragma unroll
    for (int it = 0; it < 6; ++it) {
        int q   = threadIdx.x + it * 512;   // 0..3071 chunks of 8 k
        int row = q / 96, kq = q % 96;
        const float* s = emb + (size_t)ridxL[row] * D_DIM + kq * 8;
        f32x4 f0 = *(const f32x4*)s;
        f32x4 f1 = *(const f32x4*)(s + 4);
        bf16x8 p;
        p[0]=(bf16_t)f0[0]; p[1]=(bf16_t)f0[1]; p[2]=(bf16_t)f0[2]; p[3]=(bf16_t)f0[3];
        p[4]=(bf16_t)f1[0]; p[5]=(bf16_t)f1[1]; p[6]=(bf16_t)f1[2]; p[7]=(bf16_t)f1[3];
        *(bf16x8*)(smem + row * 1536 + ((kq * 16) ^ ((row & 7) << 4))) = p;
    }
    __syncthreads();   // (2) embA visible

    // ---------------- stage 1: h = relu(emb @ w1 + b1)  [32x384] ----------
    f32x4 acc1[2][3];
#pragma unroll
    for (int rg = 0; rg < 2; ++rg)
#pragma unroll
        for (int j = 0; j < 3; ++j) acc1[rg][j] = f32x4{0.f, 0.f, 0.f, 0.f};

#pragma unroll
    for (int kf = 0; kf < 24; ++kf) {
        int kb = (kf * 32 + l4 * 8) * 2;
        bf16x8 a0 = *(const bf16x8*)(smem + l15 * 1536 + (kb ^ ((l15 & 7) << 4)));
        bf16x8 a1 = *(const bf16x8*)(smem + (l15 + 16) * 1536 + (kb ^ ((l15 & 7) << 4)));
        bf16x8 b0 = *(const bf16x8*)(w1e + ((size_t)(kf * 24 + wid * 3 + 0)) * 1024 + lane * 16);
        bf16x8 bv1 = *(const bf16x8*)(w1e + ((size_t)(kf * 24 + wid * 3 + 1)) * 1024 + lane * 16);
        bf16x8 bv2 = *(const bf16x8*)(w1e + ((size_t)(kf * 24 + wid * 3 + 2)) * 1024 + lane * 16);
        __builtin_amdgcn_s_setprio(1);
        acc1[0][0] = mfma16(a0, b0,  acc1[0][0]);
        acc1[1][0] = mfma16(a1, b0,  acc1[1][0]);
        acc1[0][1] = mfma16(a0, bv1, acc1[0][1]);
        acc1[1][1] = mfma16(a1, bv1, acc1[1][1]);
        acc1[0][2] = mfma16(a0, bv2, acc1[0][2]);
        acc1[1][2] = mfma16(a1, bv2, acc1[1][2]);
        __builtin_amdgcn_s_setprio(0);
    }
    __syncthreads();   // (3) all embA reads done; region reusable for h

    // h = relu(acc1 + b1) -> bf16 swizzled LDS @ 0 (stride 768)
#pragma unroll
    for (int jn = 0; jn < 3; ++jn) {
        int col = wid * 48 + jn * 16 + l15;
        float bb = b1[e * H_DIM + col];
#pragma unroll
        for (int rg = 0; rg < 2; ++rg)
#pragma unroll
            for (int v = 0; v < 4; ++v) {
                int row = rg * 16 + l4 * 4 + v;
                float hv = fmaxf(acc1[rg][jn][v] + bb, 0.f);
                *(bf16_t*)(smem + row * 768 + ((col * 2) ^ ((row & 7) << 4))) = (bf16_t)hv;
            }
    }
    __syncthreads();   // (4) h visible

    // ---------------- stage 2: eo = h @ w4  [32x768] ----------------------
    f32x4 acc2[2][6];
#pragma unroll
    for (int rg = 0; rg < 2; ++rg)
#pragma unroll
        for (int j = 0; j < 6; ++j) acc2[rg][j] = f32x4{0.f, 0.f, 0.f, 0.f};

#pragma unroll
    for (int kf = 0; kf < 12; ++kf) {
        int kb = (kf * 32 + l4 * 8) * 2;
        bf16x8 a0 = *(const bf16x8*)(smem + l15 * 768 + (kb ^ ((l15 & 7) << 4)));
        bf16x8 a1 = *(const bf16x8*)(smem + (l15 + 16) * 768 + (kb ^ ((l15 & 7) << 4)));
        bf16x8 b0 = *(const bf16x8*)(w4e + ((size_t)(kf * 48 + wid * 6 + 0)) * 1024 + lane * 16);
        bf16x8 bv1 = *(const bf16x8*)(w4e + ((size_t)(kf * 48 + wid * 6 + 1)) * 1024 + lane * 16);
        bf16x8 bv2 = *(const bf16x8*)(w4e + ((size_t)(kf * 48 + wid * 6 + 2)) * 1024 + lane * 16);
        bf16x8 bv3 = *(const bf16x8*)(w4e + ((size_t)(kf * 48 + wid * 6 + 3)) * 1024 + lane * 16);
        bf16x8 bv4 = *(const bf16x8*)(w4e + ((size_t)(kf * 48 + wid * 6 + 4)) * 1024 + lane * 16);
        bf16x8 bv5 = *(const bf16x8*)(w4e + ((size_t)(kf * 48 + wid * 6 + 5)) * 1024 + lane * 16);
        __builtin_amdgcn_s_setprio(1);
        acc2[0][0] = mfma16(a0, b0,  acc2[0][0]);
        acc2[1][0] = mfma16(a1, b0,  acc2[1][0]);
        acc2[0][1] = mfma16(a0, bv1, acc2[0][1]);
        acc2[1][1] = mfma16(a1, bv1, acc2[1][1]);
        acc2[0][2] = mfma16(a0, bv2, acc2[0][2]);
        acc2[1][2] = mfma16(a1, bv2, acc2[1][2]);
        acc2[0][3] = mfma16(a0, bv3, acc2[0][3]);
        acc2[1][3] = mfma16(a1, bv3, acc2[1][3]);
        acc2[0][4] = mfma16(a0, bv4, acc2[0][4]);
        acc2[1][4] = mfma16(a1, bv4, acc2[1][4]);
        acc2[0][5] = mfma16(a0, bv5, acc2[0][5]);
        acc2[1][5] = mfma16(a1, bv5, acc2[1][5]);
        __builtin_amdgcn_s_setprio(0);
    }

    // ---------------- epilogue: gate, l2norm, +emb, l2norm, scatter -------
    const int colb = wid * 96;
    float part[2][4];
#pragma unroll
    for (int rg = 0; rg < 2; ++rg)
#pragma unroll
        for (int v = 0; v < 4; ++v) part[rg][v] = 0.f;

#pragma unroll
    for (int jn = 0; jn < 6; ++jn) {
        float bb = b4[e * D_DIM + colb + jn * 16 + l15];
#pragma unroll
        for (int rg = 0; rg < 2; ++rg)
#pragma unroll
            for (int v = 0; v < 4; ++v) {
                float cv = (acc2[rg][jn][v] + bb) * gateL[rg * 16 + l4 * 4 + v];
                acc2[rg][jn][v] = cv;
                part[rg][v] += cv * cv;
            }
    }
#pragma unroll
    for (int o = 1; o < 16; o <<= 1)
#pragma unroll
        for (int rg = 0; rg < 2; ++rg)
#pragma unroll
            for (int v = 0; v < 4; ++v) part[rg][v] += __shfl_xor(part[rg][v], o, 64);
    if (l15 == 0)
#pragma unroll
        for (int rg = 0; rg < 2; ++rg)
#pragma unroll
            for (int v = 0; v < 4; ++v) ssb1[(rg * 16 + l4 * 4 + v) * 8 + wid] = part[rg][v];
    __syncthreads();   // (5) ssb1 ready

    int   rofs[2][4];   // ridx * D_DIM (int: max ~12.6M, fits)
    float inv1[2][4];
#pragma unroll
    for (int rg = 0; rg < 2; ++rg)
#pragma unroll
        for (int v = 0; v < 4; ++v) {
            int row = rg * 16 + l4 * 4 + v;
            rofs[rg][v] = ridxL[row] * D_DIM;
            float s = 0.f;
#pragma unroll
            for (int w = 0; w < 8; ++w) s += ssb1[row * 8 + w];
            inv1[rg][v] = 1.0f / fmaxf(sqrtf(s), 1e-6f);
        }

    float part2[2][4];
#pragma unroll
    for (int rg = 0; rg < 2; ++rg)
#pragma unroll
        for (int v = 0; v < 4; ++v) part2[rg][v] = 0.f;

#pragma unroll
    for (int jn = 0; jn < 6; ++jn) {
        int col = colb + jn * 16 + l15;
#pragma unroll
        for (int rg = 0; rg < 2; ++rg)
#pragma unroll
            for (int v = 0; v < 4; ++v) {
                float em = emb[rofs[rg][v] + col];
                float o2 = acc2[rg][jn][v] * inv1[rg][v] + em;
                acc2[rg][jn][v] = o2;
                part2[rg][v] += o2 * o2;
            }
    }
#pragma unroll
    for (int o = 1; o < 16; o <<= 1)
#pragma unroll
        for (int rg = 0; rg < 2; ++rg)
#pragma unroll
            for (int v = 0; v < 4; ++v) part2[rg][v] += __shfl_xor(part2[rg][v], o, 64);
    if (l15 == 0)
#pragma unroll
        for (int rg = 0; rg < 2; ++rg)
#pragma unroll
            for (int v = 0; v < 4; ++v) ssb2[(rg * 16 + l4 * 4 + v) * 8 + wid] = part2[rg][v];
    __syncthreads();   // (6) ssb2 ready

#pragma unroll
    for (int rg = 0; rg < 2; ++rg)
#pragma unroll
        for (int v = 0; v < 4; ++v) {
            int row = rg * 16 + l4 * 4 + v;
            float s = 0.f;
#pragma unroll
            for (int w = 0; w < 8; ++w) s += ssb2[row * 8 + w];
            float inv2 = 1.0f / fmaxf(sqrtf(s), 1e-12f);
            if (row < Meff) {
#pragma unroll
                for (int jn = 0; jn < 6; ++jn)
                    out[rofs[rg][v] + colb + jn * 16 + l15] = acc2[rg][jn][v] * inv2;
            }
        }
}

// ---------------------------------------------------------------------------
extern "C" void kernel_launch(void* const* d_in, const int* in_sizes, int n_in,
                              void* d_out, int out_size, void* d_ws, size_t ws_size,
                              hipStream_t stream) {
    const float* emb    = (const float*)d_in[0];
    const float* logits = (const float*)d_in[1];
    const float* w1     = (const float*)d_in[2];
    const float* b1     = (const float*)d_in[3];
    const float* w4     = (const float*)d_in[4];
    const float* b4     = (const float*)d_in[5];
    float* out = (float*)d_out;
    char*  ws  = (char*)d_ws;
    if (ws_size < WS_END) return;  // workspace too small -> fail loudly

    int*   cnt     = (int*)(ws + WS_CNT);
    int*   cur     = (int*)(ws + WS_CUR);
    int*   expert  = (int*)(ws + WS_EXP);
    float* gatev   = (float*)(ws + WS_GATE);
    int*   rowlist = (int*)(ws + WS_ROW);
    char*  w1s     = ws + WS_W1;
    char*  w4s     = ws + WS_W4;

    hipMemsetAsync(ws, 0, 512, stream);
    // weights convert (2304 blocks) + gate (32 blocks) in one dispatch
    prep<<<dim3(2336), dim3(512), 0, stream>>>(w1, w4, logits, w1s, w4s,
                                               expert, gatev, cnt);
    scatk<<<dim3(32), dim3(512), 0, stream>>>(expert, cnt, cur, rowlist);

    (void)hipFuncSetAttribute((const void*)moe_main,
                              hipFuncAttributeMaxDynamicSharedMemorySize, SMEM_BYTES);
    // max tiles = sum_e ceil(cnt_e/32) <= 527; grid 528 = 8*66 (swizzle)
    moe_main<<<dim3(528), dim3(512), SMEM_BYTES, stream>>>(
        emb, gatev, rowlist, cnt, w1s, w4s, b1, b4, out);
}